// Round 14
// baseline (88.324 us; speedup 1.0000x reference)
//
#include <hip/hip_runtime.h>

#define N_NODES 100000
#define DEG 32
#define DIM 256

typedef _Float16 f16x8 __attribute__((ext_vector_type(8)));
typedef float f32x4 __attribute__((ext_vector_type(4)));

// Wswz layout: f16x8 units, idx = (kt*16 + nt)*64 + lane, kt in [0,8), nt in [0,16).
// Unit element j holds W[kt*32 + 4*(lane>>4) + (j&3) + 16*(j>>2)][nt*16 + (lane&15)]
// (B fragment for mfma_f32_16x16x32_f16; A uses the identical (lane,j)->k map, so
//  any k-permutation error cancels in the contraction.)
__global__ void wprep_kernel(const float* __restrict__ W, _Float16* __restrict__ Wswz) {
    int tid = blockIdx.x * blockDim.x + threadIdx.x;  // 0..8191
    int l = tid & 63;
    int frag = tid >> 6;
    int kt = frag >> 4;
    int nt = frag & 15;
    int col = nt * 16 + (l & 15);
    int kbase = kt * 32 + ((l >> 4) << 2);
    f16x8 v;
#pragma unroll
    for (int j = 0; j < 8; ++j) {
        int k = kbase + (j & 3) + ((j >> 2) << 4);
        v[j] = (_Float16)W[(size_t)k * DIM + col];
    }
    *reinterpret_cast<f16x8*>(Wswz + (size_t)tid * 8) = v;
}

__device__ __forceinline__ f16x8 cvt_a(float4 lo, float4 hi) {
    f16x8 af;
    af[0] = (_Float16)lo.x; af[1] = (_Float16)lo.y;
    af[2] = (_Float16)lo.z; af[3] = (_Float16)lo.w;
    af[4] = (_Float16)hi.x; af[5] = (_Float16)hi.y;
    af[6] = (_Float16)hi.z; af[7] = (_Float16)hi.w;
    return af;
}

// Block = 256 threads (4 waves). Tile = 128 rows x 256 cols in EIGHT 32-col
// phases, double-buffered B (2 x 16 KB), ONE barrier per phase (r12 schedule).
// Wave wv owns a DISJOINT 32-row pair of 16-row strips (no duplicated A loads,
// unlike round 10); every B fragment read from LDS feeds TWO MFMAs (one per
// strip) -> per-output LDS traffic HALVED vs r12 (~19us -> ~10us per CU).
// A held in f16 regs (64 VGPR); amax/amin in regs via in-wave shuffles.
__launch_bounds__(256, 4)
__global__ void agg_kernel(const float* __restrict__ F, const float* __restrict__ Adj,
                           const _Float16* __restrict__ Wswz, float* __restrict__ out) {
    __shared__ _Float16 sB[2][16 * 64 * 8];   // 2 x 16384 B: chunk c=kt*2+np at ((c*64)+l)*8

    const int bx = blockIdx.x;
    const int m0 = bx * 128;
    const int t  = threadIdx.x;
    const int wv = t >> 6;
    const int l  = t & 63;
    const int lg = l >> 4;
    const int ll = l & 15;

    // ---- stage phase-0 chunks into buffer 0 ----
#pragma unroll
    for (int i = 0; i < 4; ++i) {
        int c = wv * 4 + i;                 // c = kt*2 + np
        int kt = c >> 1, np = c & 1;
        int srcfrag = kt * 16 + np;         // phase 0: nt = np
        f16x8 v = *reinterpret_cast<const f16x8*>(Wswz + ((size_t)srcfrag * 64 + l) * 8);
        *reinterpret_cast<f16x8*>(&sB[0][((size_t)c * 64 + l) * 8]) = v;
    }

    // ---- adjacency: wave reduces its OWN 32 rows (2 lanes/row, 64 B each) ----
    const int arow = l >> 1;                // 0..31 local row within wave
    const int q    = l & 1;
    int radj = m0 + wv * 32 + arow;
    radj = radj < N_NODES ? radj : (N_NODES - 1);
    const float4* ap = reinterpret_cast<const float4*>(Adj + (size_t)radj * DEG) + q * 4;
    float4 ad0 = ap[0], ad1 = ap[1], ad2 = ap[2], ad3 = ap[3];

    // ---- A strip 0 loads (16 rows x 16 dwordx4 per lane) ----
    int rowA0 = m0 + wv * 32 + ll;
    rowA0 = rowA0 < N_NODES ? rowA0 : (N_NODES - 1);
    const float4* Af0 = reinterpret_cast<const float4*>(F + (size_t)rowA0 * DIM) + lg;
    float4 plo[8], phi[8];
#pragma unroll
    for (int kt = 0; kt < 8; ++kt) { plo[kt] = Af0[kt * 8]; phi[kt] = Af0[kt * 8 + 4]; }

    // ---- adjacency reduce in-wave (waits adj only; A0 still in flight) ----
    float mx = fmaxf(fmaxf(ad0.x, ad0.y), fmaxf(ad0.z, ad0.w));
    mx = fmaxf(mx, fmaxf(fmaxf(ad1.x, ad1.y), fmaxf(ad1.z, ad1.w)));
    mx = fmaxf(mx, fmaxf(fmaxf(ad2.x, ad2.y), fmaxf(ad2.z, ad2.w)));
    mx = fmaxf(mx, fmaxf(fmaxf(ad3.x, ad3.y), fmaxf(ad3.z, ad3.w)));
    float mn = fminf(fminf(ad0.x, ad0.y), fminf(ad0.z, ad0.w));
    mn = fminf(mn, fminf(fminf(ad1.x, ad1.y), fminf(ad1.z, ad1.w)));
    mn = fminf(mn, fminf(fminf(ad2.x, ad2.y), fminf(ad2.z, ad2.w)));
    mn = fminf(mn, fminf(fminf(ad3.x, ad3.y), fminf(ad3.z, ad3.w)));
    mx = fmaxf(mx, __shfl_xor(mx, 1));
    mn = fminf(mn, __shfl_xor(mn, 1));
    // strip s, acc-reg r -> local row s*16+4*lg+r, reduced by lanes 2*row, 2*row+1
    float amaxr[2][4], aminr[2][4];
#pragma unroll
    for (int s = 0; s < 2; ++s)
#pragma unroll
        for (int r = 0; r < 4; ++r) {
            amaxr[s][r] = __shfl(mx, 2 * (s * 16 + 4 * lg + r));
            aminr[s][r] = __shfl(mn, 2 * (s * 16 + 4 * lg + r));
        }

    // ---- convert strip 0, then load+convert strip 1 (caps VGPR peak) ----
    f16x8 a16[2][8];
#pragma unroll
    for (int kt = 0; kt < 8; ++kt) a16[0][kt] = cvt_a(plo[kt], phi[kt]);

    int rowA1 = m0 + wv * 32 + 16 + ll;
    rowA1 = rowA1 < N_NODES ? rowA1 : (N_NODES - 1);
    const float4* Af1 = reinterpret_cast<const float4*>(F + (size_t)rowA1 * DIM) + lg;
#pragma unroll
    for (int kt = 0; kt < 8; ++kt) { plo[kt] = Af1[kt * 8]; phi[kt] = Af1[kt * 8 + 4]; }
#pragma unroll
    for (int kt = 0; kt < 8; ++kt) a16[1][kt] = cvt_a(plo[kt], phi[kt]);

    __syncthreads();   // sB[0] visible

    const int rbase = 4 * lg;

    for (int p = 0; p < 8; ++p) {
        // ---- issue next phase's stage loads FIRST (vmcnt; hides under compute) ----
        f16x8 sv[4];
        if (p < 7) {
#pragma unroll
            for (int i = 0; i < 4; ++i) {
                int c = wv * 4 + i;
                int kt = c >> 1, np = c & 1;
                int srcfrag = kt * 16 + (p + 1) * 2 + np;
                sv[i] = *reinterpret_cast<const f16x8*>(Wswz + ((size_t)srcfrag * 64 + l) * 8);
            }
        }

        // ---- compute from sB[p&1]: each B fragment feeds BOTH strips ----
        const f16x8* Bl = reinterpret_cast<const f16x8*>(&sB[p & 1][0]) + l;
        f32x4 acc[2][2];
#pragma unroll
        for (int s = 0; s < 2; ++s)
#pragma unroll
            for (int np = 0; np < 2; ++np) acc[s][np] = (f32x4){0.f, 0.f, 0.f, 0.f};
#pragma unroll
        for (int kt = 0; kt < 8; ++kt) {
#pragma unroll
            for (int np = 0; np < 2; ++np) {
                f16x8 b = Bl[(kt * 2 + np) * 64];
                acc[0][np] = __builtin_amdgcn_mfma_f32_16x16x32_f16(a16[0][kt], b, acc[0][np], 0, 0, 0);
                acc[1][np] = __builtin_amdgcn_mfma_f32_16x16x32_f16(a16[1][kt], b, acc[1][np], 0, 0, 0);
            }
        }

        // ---- epilogue stores for phase p ----
#pragma unroll
        for (int s = 0; s < 2; ++s)
#pragma unroll
            for (int r = 0; r < 4; ++r) {
                const int row = m0 + wv * 32 + s * 16 + rbase + r;
                if (row < N_NODES) {
                    float* orow = out + (size_t)row * DIM + p * 32 + ll;
#pragma unroll
                    for (int np = 0; np < 2; ++np) {
                        float v = acc[s][np][r];
                        orow[np * 16] = fmaxf(fmaxf(amaxr[s][r] * v, aminr[s][r] * v), 0.0f);
                    }
                }
            }

        // ---- write staged regs into the OTHER buffer (safe pre-barrier) ----
        if (p < 7) {
#pragma unroll
            for (int i = 0; i < 4; ++i) {
                int c = wv * 4 + i;
                *reinterpret_cast<f16x8*>(&sB[(p + 1) & 1][((size_t)c * 64 + l) * 8]) = sv[i];
            }
            __syncthreads();   // single barrier per phase
        }
    }
}

extern "C" void kernel_launch(void* const* d_in, const int* in_sizes, int n_in,
                              void* d_out, int out_size, void* d_ws, size_t ws_size,
                              hipStream_t stream) {
    const float* F   = (const float*)d_in[0];
    const float* Adj = (const float*)d_in[1];
    const float* W   = (const float*)d_in[2];
    float* out = (float*)d_out;
    _Float16* Wswz = (_Float16*)d_ws;   // 256*256*2 = 128 KB

    hipLaunchKernelGGL(wprep_kernel, dim3(32), dim3(256), 0, stream, W, Wswz);
    const int nblk = (N_NODES + 127) / 128;   // 782
    hipLaunchKernelGGL(agg_kernel, dim3(nblk), dim3(256), 0, stream, F, Adj, Wswz, out);
}

// Round 15
// 56.909 us; speedup vs baseline: 1.5520x; 1.5520x over previous
//
#include <hip/hip_runtime.h>

#define N_NODES 100000
#define DEG 32
#define DIM 256

typedef _Float16 f16x8 __attribute__((ext_vector_type(8)));
typedef float f32x4 __attribute__((ext_vector_type(4)));

// Wswz layout: f16x8 units, idx = (kt*16 + nt)*64 + lane, kt in [0,8), nt in [0,16).
// Unit element j holds W[kt*32 + 4*(lane>>4) + (j&3) + 16*(j>>2)][nt*16 + (lane&15)]
// (B fragment for mfma_f32_16x16x32_f16; A uses the identical (lane,j)->k map, so
//  any k-permutation error cancels in the contraction.)
__global__ void wprep_kernel(const float* __restrict__ W, _Float16* __restrict__ Wswz) {
    int tid = blockIdx.x * blockDim.x + threadIdx.x;  // 0..8191
    int l = tid & 63;
    int frag = tid >> 6;
    int kt = frag >> 4;
    int nt = frag & 15;
    int col = nt * 16 + (l & 15);
    int kbase = kt * 32 + ((l >> 4) << 2);
    f16x8 v;
#pragma unroll
    for (int j = 0; j < 8; ++j) {
        int k = kbase + (j & 3) + ((j >> 2) << 4);
        v[j] = (_Float16)W[(size_t)k * DIM + col];
    }
    *reinterpret_cast<f16x8*>(Wswz + (size_t)tid * 8) = v;
}

__device__ __forceinline__ f16x8 cvt_a(float4 lo, float4 hi) {
    f16x8 af;
    af[0] = (_Float16)lo.x; af[1] = (_Float16)lo.y;
    af[2] = (_Float16)lo.z; af[3] = (_Float16)lo.w;
    af[4] = (_Float16)hi.x; af[5] = (_Float16)hi.y;
    af[6] = (_Float16)hi.z; af[7] = (_Float16)hi.w;
    return af;
}

// Block = 128 threads (2 waves). Tile = 64 rows x 256 cols in EIGHT 32-col
// phases, double-buffered B (2 x 16 KB), ONE barrier per phase. Each wave
// owns 32 rows (two 16-row strips): every B fragment ds_read feeds TWO
// MFMAs -> per-CU LDS-read traffic HALVED vs r12 (the largest non-HBM
// serial term, ~16us). Spill vectors from r10/r14 fixed: grid stays 1563
// (2-wave blocks, no tail regression), sched_barrier(0) stops the compiler
// hoisting strip-1 A-loads over strip-0 cvt, and staging is split 4+4
// chunks (16-reg transient). A in f16 regs; amax/amin in regs via shuffles.
__launch_bounds__(128, 4)
__global__ void agg_kernel(const float* __restrict__ F, const float* __restrict__ Adj,
                           const _Float16* __restrict__ Wswz, float* __restrict__ out) {
    __shared__ _Float16 sB[2][16 * 64 * 8];   // 2 x 16384 B: chunk c=kt*2+np at ((c*64)+l)*8

    const int bx = blockIdx.x;
    const int m0 = bx * 64;
    const int t  = threadIdx.x;
    const int wv = t >> 6;        // 0..1
    const int l  = t & 63;
    const int lg = l >> 4;
    const int ll = l & 15;

    // ---- adjacency loads: wave's own 32 rows, 2 lanes/row, 4 float4 each ----
    const int arow = l >> 1;      // 0..31
    const int q    = l & 1;
    int radj = m0 + wv * 32 + arow;
    radj = radj < N_NODES ? radj : (N_NODES - 1);
    const float4* ap = reinterpret_cast<const float4*>(Adj + (size_t)radj * DEG) + q * 4;
    float4 ad0 = ap[0], ad1 = ap[1], ad2 = ap[2], ad3 = ap[3];

    // ---- stage loads, first 4 chunks (c = wv*8 + i) ----
    f16x8 sv[4];
#pragma unroll
    for (int i = 0; i < 4; ++i) {
        int c = wv * 8 + i;
        int kt = c >> 1, np = c & 1;
        int srcfrag = kt * 16 + np;          // phase 0: nt = np
        sv[i] = *reinterpret_cast<const f16x8*>(Wswz + ((size_t)srcfrag * 64 + l) * 8);
    }

    // ---- A strip 0 loads ----
    int rowA0 = m0 + wv * 32 + ll;
    rowA0 = rowA0 < N_NODES ? rowA0 : (N_NODES - 1);
    const float4* Af0 = reinterpret_cast<const float4*>(F + (size_t)rowA0 * DIM) + lg;
    float4 plo[8], phi[8];
#pragma unroll
    for (int kt = 0; kt < 8; ++kt) { plo[kt] = Af0[kt * 8]; phi[kt] = Af0[kt * 8 + 4]; }

    // ---- adjacency reduce (waits adj only; sv+A0 still in flight) ----
    float mx = fmaxf(fmaxf(ad0.x, ad0.y), fmaxf(ad0.z, ad0.w));
    mx = fmaxf(mx, fmaxf(fmaxf(ad1.x, ad1.y), fmaxf(ad1.z, ad1.w)));
    mx = fmaxf(mx, fmaxf(fmaxf(ad2.x, ad2.y), fmaxf(ad2.z, ad2.w)));
    mx = fmaxf(mx, fmaxf(fmaxf(ad3.x, ad3.y), fmaxf(ad3.z, ad3.w)));
    float mn = fminf(fminf(ad0.x, ad0.y), fminf(ad0.z, ad0.w));
    mn = fminf(mn, fminf(fminf(ad1.x, ad1.y), fminf(ad1.z, ad1.w)));
    mn = fminf(mn, fminf(fminf(ad2.x, ad2.y), fminf(ad2.z, ad2.w)));
    mn = fminf(mn, fminf(fminf(ad3.x, ad3.y), fminf(ad3.z, ad3.w)));
    mx = fmaxf(mx, __shfl_xor(mx, 1));
    mn = fminf(mn, __shfl_xor(mn, 1));
    // strip s, acc-reg r -> local row s*16+4*lg+r, reduced by lane 2*row
    float amaxr[2][4], aminr[2][4];
#pragma unroll
    for (int s = 0; s < 2; ++s)
#pragma unroll
        for (int r = 0; r < 4; ++r) {
            amaxr[s][r] = __shfl(mx, 2 * (s * 16 + 4 * lg + r));
            aminr[s][r] = __shfl(mn, 2 * (s * 16 + 4 * lg + r));
        }

    // ---- write stage chunks 0..3 into buf 0; issue chunks 4..7 ----
#pragma unroll
    for (int i = 0; i < 4; ++i) {
        int c = wv * 8 + i;
        *reinterpret_cast<f16x8*>(&sB[0][((size_t)c * 64 + l) * 8]) = sv[i];
    }
#pragma unroll
    for (int i = 0; i < 4; ++i) {
        int c = wv * 8 + 4 + i;
        int kt = c >> 1, np = c & 1;
        int srcfrag = kt * 16 + np;
        sv[i] = *reinterpret_cast<const f16x8*>(Wswz + ((size_t)srcfrag * 64 + l) * 8);
    }

    // ---- cvt strip 0 (frees plo/phi), then fence against load hoisting ----
    f16x8 a16[2][8];
#pragma unroll
    for (int kt = 0; kt < 8; ++kt) a16[0][kt] = cvt_a(plo[kt], phi[kt]);
    __builtin_amdgcn_sched_barrier(0);

    // ---- write stage chunks 4..7 (frees sv before A1 transient) ----
#pragma unroll
    for (int i = 0; i < 4; ++i) {
        int c = wv * 8 + 4 + i;
        *reinterpret_cast<f16x8*>(&sB[0][((size_t)c * 64 + l) * 8]) = sv[i];
    }
    __builtin_amdgcn_sched_barrier(0);

    // ---- A strip 1 load + cvt ----
    int rowA1 = m0 + wv * 32 + 16 + ll;
    rowA1 = rowA1 < N_NODES ? rowA1 : (N_NODES - 1);
    const float4* Af1 = reinterpret_cast<const float4*>(F + (size_t)rowA1 * DIM) + lg;
#pragma unroll
    for (int kt = 0; kt < 8; ++kt) { plo[kt] = Af1[kt * 8]; phi[kt] = Af1[kt * 8 + 4]; }
#pragma unroll
    for (int kt = 0; kt < 8; ++kt) a16[1][kt] = cvt_a(plo[kt], phi[kt]);

    __syncthreads();   // sB[0] visible

    const int rbase = 4 * lg;

    for (int p = 0; p < 8; ++p) {
        const f16x8* Bl = reinterpret_cast<const f16x8*>(&sB[p & 1][0]) + l;
        f32x4 acc[2][2];
#pragma unroll
        for (int s = 0; s < 2; ++s)
#pragma unroll
            for (int np = 0; np < 2; ++np) acc[s][np] = (f32x4){0.f, 0.f, 0.f, 0.f};

        // ---- issue next phase's stage chunks 0..3 ----
        f16x8 s1[4];
        if (p < 7) {
#pragma unroll
            for (int i = 0; i < 4; ++i) {
                int c = wv * 8 + i;
                int kt = c >> 1, np = c & 1;
                int srcfrag = kt * 16 + (p + 1) * 2 + np;
                s1[i] = *reinterpret_cast<const f16x8*>(Wswz + ((size_t)srcfrag * 64 + l) * 8);
            }
        }

        // ---- compute kt 0..3: each B read feeds both strips ----
#pragma unroll
        for (int kt = 0; kt < 4; ++kt) {
#pragma unroll
            for (int np = 0; np < 2; ++np) {
                f16x8 b = Bl[(kt * 2 + np) * 64];
                acc[0][np] = __builtin_amdgcn_mfma_f32_16x16x32_f16(a16[0][kt], b, acc[0][np], 0, 0, 0);
                acc[1][np] = __builtin_amdgcn_mfma_f32_16x16x32_f16(a16[1][kt], b, acc[1][np], 0, 0, 0);
            }
        }

        // ---- write s1 into other buffer; issue chunks 4..7 ----
        if (p < 7) {
#pragma unroll
            for (int i = 0; i < 4; ++i) {
                int c = wv * 8 + i;
                *reinterpret_cast<f16x8*>(&sB[(p + 1) & 1][((size_t)c * 64 + l) * 8]) = s1[i];
            }
#pragma unroll
            for (int i = 0; i < 4; ++i) {
                int c = wv * 8 + 4 + i;
                int kt = c >> 1, np = c & 1;
                int srcfrag = kt * 16 + (p + 1) * 2 + np;
                s1[i] = *reinterpret_cast<const f16x8*>(Wswz + ((size_t)srcfrag * 64 + l) * 8);
            }
        }

        // ---- compute kt 4..7 ----
#pragma unroll
        for (int kt = 4; kt < 8; ++kt) {
#pragma unroll
            for (int np = 0; np < 2; ++np) {
                f16x8 b = Bl[(kt * 2 + np) * 64];
                acc[0][np] = __builtin_amdgcn_mfma_f32_16x16x32_f16(a16[0][kt], b, acc[0][np], 0, 0, 0);
                acc[1][np] = __builtin_amdgcn_mfma_f32_16x16x32_f16(a16[1][kt], b, acc[1][np], 0, 0, 0);
            }
        }

        // ---- epilogue stores for phase p ----
#pragma unroll
        for (int s = 0; s < 2; ++s)
#pragma unroll
            for (int r = 0; r < 4; ++r) {
                const int row = m0 + wv * 32 + s * 16 + rbase + r;
                if (row < N_NODES) {
                    float* orow = out + (size_t)row * DIM + p * 32 + ll;
#pragma unroll
                    for (int np = 0; np < 2; ++np) {
                        float v = acc[s][np][r];
                        orow[np * 16] = fmaxf(fmaxf(amaxr[s][r] * v, aminr[s][r] * v), 0.0f);
                    }
                }
            }

        // ---- write staged chunks 4..7, single barrier per phase ----
        if (p < 7) {
#pragma unroll
            for (int i = 0; i < 4; ++i) {
                int c = wv * 8 + 4 + i;
                *reinterpret_cast<f16x8*>(&sB[(p + 1) & 1][((size_t)c * 64 + l) * 8]) = s1[i];
            }
            __syncthreads();
        }
    }
}

extern "C" void kernel_launch(void* const* d_in, const int* in_sizes, int n_in,
                              void* d_out, int out_size, void* d_ws, size_t ws_size,
                              hipStream_t stream) {
    const float* F   = (const float*)d_in[0];
    const float* Adj = (const float*)d_in[1];
    const float* W   = (const float*)d_in[2];
    float* out = (float*)d_out;
    _Float16* Wswz = (_Float16*)d_ws;   // 256*256*2 = 128 KB

    hipLaunchKernelGGL(wprep_kernel, dim3(32), dim3(256), 0, stream, W, Wswz);
    const int nblk = (N_NODES + 63) / 64;   // 1563
    hipLaunchKernelGGL(agg_kernel, dim3(nblk), dim3(128), 0, stream, F, Adj, Wswz, out);
}

// Round 16
// 48.896 us; speedup vs baseline: 1.8064x; 1.1639x over previous
//
#include <hip/hip_runtime.h>

#define N_NODES 100000
#define DEG 32
#define DIM 256

typedef _Float16 f16x8 __attribute__((ext_vector_type(8)));
typedef float f32x4 __attribute__((ext_vector_type(4)));

// Wswz layout: f16x8 units, idx = (kt*16 + nt)*64 + lane, kt in [0,8), nt in [0,16).
// Unit element j holds W[kt*32 + 4*(lane>>4) + (j&3) + 16*(j>>2)][nt*16 + (lane&15)]
// (B fragment for mfma_f32_16x16x32_f16; A uses the identical (lane,j)->k map, so
//  any k-permutation error cancels in the contraction.)
__global__ void wprep_kernel(const float* __restrict__ W, _Float16* __restrict__ Wswz) {
    int tid = blockIdx.x * blockDim.x + threadIdx.x;  // 0..8191
    int l = tid & 63;
    int frag = tid >> 6;
    int kt = frag >> 4;
    int nt = frag & 15;
    int col = nt * 16 + (l & 15);
    int kbase = kt * 32 + ((l >> 4) << 2);
    f16x8 v;
#pragma unroll
    for (int j = 0; j < 8; ++j) {
        int k = kbase + (j & 3) + ((j >> 2) << 4);
        v[j] = (_Float16)W[(size_t)k * DIM + col];
    }
    *reinterpret_cast<f16x8*>(Wswz + (size_t)tid * 8) = v;
}

__device__ __forceinline__ f16x8 cvt_a(float4 lo, float4 hi) {
    f16x8 af;
    af[0] = (_Float16)lo.x; af[1] = (_Float16)lo.y;
    af[2] = (_Float16)lo.z; af[3] = (_Float16)lo.w;
    af[4] = (_Float16)hi.x; af[5] = (_Float16)hi.y;
    af[6] = (_Float16)hi.z; af[7] = (_Float16)hi.w;
    return af;
}

// BEST-KNOWN CONFIG (round 12, 49.0 us): Block = 256 threads (4 waves).
// Tile = 64 rows x 256 cols in EIGHT 32-col phases, DOUBLE-BUFFERED B
// (2 x 16 KB LDS): phase p issues p+1's stage loads first (vmcnt), computes
// from sB[p&1] (lgkmcnt), stores, then ds_writes the staged regs into
// sB[(p+1)&1]. ONE barrier per phase. A held in f16 regs across all phases;
// amax/amin in regs via in-wave shuffles. VGPR 48, no spill.
__launch_bounds__(256, 4)
__global__ void agg_kernel(const float* __restrict__ F, const float* __restrict__ Adj,
                           const _Float16* __restrict__ Wswz, float* __restrict__ out) {
    __shared__ _Float16 sB[2][16 * 64 * 8];   // 2 x 16384 B: chunk c=kt*2+np at ((c*64)+l)*8

    const int bx = blockIdx.x;
    const int m0 = bx * 64;
    const int t  = threadIdx.x;
    const int wv = t >> 6;
    const int l  = t & 63;
    const int lg = l >> 4;
    const int ll = l & 15;

    // ---- stage B chunk for phase 0 into buffer 0 ----
#pragma unroll
    for (int i = 0; i < 4; ++i) {
        int c = wv * 4 + i;                 // c = kt*2 + np
        int kt = c >> 1, np = c & 1;
        int srcfrag = kt * 16 + np;         // phase 0: nt = np
        f16x8 v = *reinterpret_cast<const f16x8*>(Wswz + ((size_t)srcfrag * 64 + l) * 8);
        *reinterpret_cast<f16x8*>(&sB[0][((size_t)c * 64 + l) * 8]) = v;
    }

    // ---- adjacency: wave reduces its OWN 16 rows (4 lanes/row, 32 B each) ----
    const int rrow = l >> 2;                // 0..15 local row within wave
    const int q    = l & 3;
    int radj = m0 + wv * 16 + rrow;
    radj = radj < N_NODES ? radj : (N_NODES - 1);
    const float4* ap = reinterpret_cast<const float4*>(Adj + (size_t)radj * DEG) + q * 2;
    float4 ad0 = ap[0], ad1 = ap[1];

    // ---- A burst: 16 dwordx4 per lane ----
    int rowA = m0 + wv * 16 + ll;
    rowA = rowA < N_NODES ? rowA : (N_NODES - 1);
    const float4* Af4 = reinterpret_cast<const float4*>(F + (size_t)rowA * DIM) + lg;
    float4 plo[8], phi[8];
#pragma unroll
    for (int kt = 0; kt < 8; ++kt) { plo[kt] = Af4[kt * 8]; phi[kt] = Af4[kt * 8 + 4]; }

    // ---- adjacency reduce in-wave (waits adj only; A still in flight) ----
    float mx = fmaxf(fmaxf(ad0.x, ad0.y), fmaxf(ad0.z, ad0.w));
    mx = fmaxf(mx, fmaxf(fmaxf(ad1.x, ad1.y), fmaxf(ad1.z, ad1.w)));
    float mn = fminf(fminf(ad0.x, ad0.y), fminf(ad0.z, ad0.w));
    mn = fminf(mn, fminf(fminf(ad1.x, ad1.y), fminf(ad1.z, ad1.w)));
    mx = fmaxf(mx, __shfl_xor(mx, 1)); mn = fminf(mn, __shfl_xor(mn, 1));
    mx = fmaxf(mx, __shfl_xor(mx, 2)); mn = fminf(mn, __shfl_xor(mn, 2));
    // epilogue row (wv*16 + 4*lg + r) was reduced by lane 16*lg+4*r
    float amaxr[4], aminr[4];
#pragma unroll
    for (int r = 0; r < 4; ++r) {
        amaxr[r] = __shfl(mx, 16 * lg + 4 * r);
        aminr[r] = __shfl(mn, 16 * lg + 4 * r);
    }

    // ---- convert A to f16 fragments ----
    f16x8 a16[8];
#pragma unroll
    for (int kt = 0; kt < 8; ++kt) a16[kt] = cvt_a(plo[kt], phi[kt]);

    __syncthreads();   // sB[0] visible

    const int rbase = wv * 16 + 4 * lg;

    for (int p = 0; p < 8; ++p) {
        // ---- issue next chunk's stage loads FIRST (vmcnt; hides under compute) ----
        f16x8 sv[4];
        if (p < 7) {
#pragma unroll
            for (int i = 0; i < 4; ++i) {
                int c = wv * 4 + i;
                int kt = c >> 1, np = c & 1;
                int srcfrag = kt * 16 + (p + 1) * 2 + np;
                sv[i] = *reinterpret_cast<const f16x8*>(Wswz + ((size_t)srcfrag * 64 + l) * 8);
            }
        }

        // ---- compute from sB[p&1] (lgkmcnt stream, independent of sv loads) ----
        const f16x8* Bl = reinterpret_cast<const f16x8*>(&sB[p & 1][0]) + l;
        f32x4 acc[2];
        acc[0] = (f32x4){0.f, 0.f, 0.f, 0.f};
        acc[1] = (f32x4){0.f, 0.f, 0.f, 0.f};
#pragma unroll
        for (int kt = 0; kt < 8; ++kt) {
#pragma unroll
            for (int np = 0; np < 2; ++np) {
                f16x8 b = Bl[(kt * 2 + np) * 64];
                acc[np] = __builtin_amdgcn_mfma_f32_16x16x32_f16(a16[kt], b, acc[np], 0, 0, 0);
            }
        }

        // ---- epilogue stores for phase p ----
#pragma unroll
        for (int r = 0; r < 4; ++r) {
            const int row = m0 + rbase + r;
            if (row < N_NODES) {
                float* orow = out + (size_t)row * DIM + p * 32 + ll;
#pragma unroll
                for (int np = 0; np < 2; ++np) {
                    float v = acc[np][r];
                    orow[np * 16] = fmaxf(fmaxf(amaxr[r] * v, aminr[r] * v), 0.0f);
                }
            }
        }

        // ---- write staged regs into the OTHER buffer (safe pre-barrier:
        //      phase p-1's readers of this buffer were fenced already) ----
        if (p < 7) {
#pragma unroll
            for (int i = 0; i < 4; ++i) {
                int c = wv * 4 + i;
                *reinterpret_cast<f16x8*>(&sB[(p + 1) & 1][((size_t)c * 64 + l) * 8]) = sv[i];
            }
            __syncthreads();   // single barrier per phase
        }
    }
}

extern "C" void kernel_launch(void* const* d_in, const int* in_sizes, int n_in,
                              void* d_out, int out_size, void* d_ws, size_t ws_size,
                              hipStream_t stream) {
    const float* F   = (const float*)d_in[0];
    const float* Adj = (const float*)d_in[1];
    const float* W   = (const float*)d_in[2];
    float* out = (float*)d_out;
    _Float16* Wswz = (_Float16*)d_ws;   // 256*256*2 = 128 KB

    hipLaunchKernelGGL(wprep_kernel, dim3(32), dim3(256), 0, stream, W, Wswz);
    const int nblk = (N_NODES + 63) / 64;   // 1563
    hipLaunchKernelGGL(agg_kernel, dim3(nblk), dim3(256), 0, stream, F, Adj, Wswz, out);
}